// Round 2
// baseline (561.725 us; speedup 1.0000x reference)
//
#include <hip/hip_runtime.h>

// PWC-Net correlation (md=4, 81 disps) + leaky_relu(0.1), mean over C=256.
// B=8 C=256 H=96 W=128, f32 in/out.
//
// Block = 9 waves (576 thr), one wave per dy. Tile = 4 rows x 128 w.
// Lane owns 8 consecutive w pixels x 9 dx = 72 f32 accumulators.
// Channels processed in chunks of 8, packed as f16 pairs in LDS,
// consumed via v_dot2_f32_f16 (2 MACs/instr, f32 accumulate).
// XOR bank swizzle on LDS; XCD==batch block mapping for L2 reuse of the
// 12-row x2 window shared between h-adjacent blocks.

#define B_ 8
#define C_ 256
#define H_ 96
#define W_ 128
#define TH 4
#define CC 8
#define NCH (C_ / CC)          // 32 chunks
#define HW (H_ * W_)
#define CHSTRIDE ((size_t)CC * HW)

typedef __fp16 h2_t __attribute__((ext_vector_type(2)));

union H2U { unsigned int u; h2_t h; };

__device__ __forceinline__ h2_t u_as_h2(unsigned int u) { H2U x; x.u = u; return x.h; }

__device__ __forceinline__ unsigned int packh2(float a, float b) {
    H2U x; x.h = __builtin_amdgcn_cvt_pkrtz(a, b); return x.u;
}

#if __has_builtin(__builtin_amdgcn_fdot2)
__device__ __forceinline__ float dot2(unsigned int a, unsigned int b, float c) {
    return __builtin_amdgcn_fdot2(u_as_h2(a), u_as_h2(b), c, false);
}
#else
__device__ __forceinline__ float dot2(unsigned int a, unsigned int b, float c) {
    h2_t ha = u_as_h2(a), hb = u_as_h2(b);
    return c + (float)ha[0] * (float)hb[0] + (float)ha[1] * (float)hb[1];
}
#endif

// LDS index helpers (u32 units). Swizzle: within each 8-slot (32 u32 = 128B)
// group, slot p is stored at p ^ (group&7) [^ (row&7) for x2].
__device__ __forceinline__ int x1_idx(int r, int w, int cp) {
    return r * 512 + (w >> 3) * 32 + ((((w & 7) ^ ((w >> 3) & 7))) << 2) + cp;
}
__device__ __forceinline__ int x2_idx(int r, int s, int cp) {
    return r * 544 + (s >> 3) * 32 + ((((s & 7) ^ ((s >> 3) & 7) ^ (r & 7))) << 2) + cp;
}

__global__ __launch_bounds__(576, 3)
void corr_kernel(const float* __restrict__ x1, const float* __restrict__ x2,
                 float* __restrict__ out)
{
    __shared__ __align__(16) unsigned int s1[TH * 128 * 4];   // 2048 u32 = 8 KB
    __shared__ __align__(16) unsigned int s2[12 * 544];       // 6528 u32 = 25.5 KB

    const int bid = blockIdx.x;
    const int b   = bid & 7;          // XCD == batch (round-robin dispatch)
    const int h0  = (bid >> 3) * TH;
    const int tid = threadIdx.x;
    const int dy  = tid >> 6;         // wave id = dy (0..8)
    const int lane = tid & 63;
    const int hr  = lane >> 4;        // 0..3  (h row within tile)
    const int wq  = lane & 15;        // 16 groups of 8 w pixels

    // zero x2 LDS once; invalid (padding) slots are never written again
    for (int i = tid; i < 12 * 544; i += 576) s2[i] = 0u;

    // ---------------- staging task setup (fixed per thread) ----------------
    // x1: tid<512 -> (cpx fastest, then w4, then row)
    const int cpx = tid & 3;
    const int w4  = (tid >> 2) & 31;
    const int rx  = (tid >> 7) & 3;
    const bool x1act = (tid < 512);
    const float* a0p = x1 + (((size_t)(b * C_ + 2 * cpx)) * H_ + (h0 + rx)) * W_ + w4 * 4;
    int s1i[4];
    #pragma unroll
    for (int k = 0; k < 4; ++k) s1i[k] = x1_idx(rx, w4 * 4 + k, cpx);

    // x2: 1632 float4-pair tasks = 4cp x 34groups x 12rows, 3 rounds of 576
    const float* b0p[3];
    int  s2i[3][4];
    bool xval[3];
    #pragma unroll
    for (int i = 0; i < 3; ++i) {
        int u = tid + i * 576;
        bool act = (u < 1632);
        int cp2  = u & 3;
        int rest = u >> 2;            // 0..407 when active
        int g = rest % 34;
        int r = rest / 34;
        if (!act) { cp2 = 0; g = 1; r = 0; }
        int hh = h0 + r - 4;
        bool v = act && (hh >= 0) && (hh < H_) && (g >= 1) && (g <= 32);
        xval[i] = v;
        int hhc = v ? hh : 0;
        b0p[i] = x2 + (((size_t)(b * C_ + 2 * cp2)) * H_ + hhc) * W_ + (g * 4 - 4);
        #pragma unroll
        for (int k = 0; k < 4; ++k) s2i[i][k] = x2_idx(r, g * 4 + k, cp2);
    }

    // prefetch registers
    float4 pa0, pa1, pb0[3], pb1[3];

    auto LOAD = [&](size_t off) {
        if (x1act) {
            pa0 = *reinterpret_cast<const float4*>(a0p + off);
            pa1 = *reinterpret_cast<const float4*>(a0p + off + HW);
        }
        #pragma unroll
        for (int i = 0; i < 3; ++i) {
            if (xval[i]) {
                pb0[i] = *reinterpret_cast<const float4*>(b0p[i] + off);
                pb1[i] = *reinterpret_cast<const float4*>(b0p[i] + off + HW);
            }
        }
    };
    auto WRITE = [&]() {
        if (x1act) {
            s1[s1i[0]] = packh2(pa0.x, pa1.x);
            s1[s1i[1]] = packh2(pa0.y, pa1.y);
            s1[s1i[2]] = packh2(pa0.z, pa1.z);
            s1[s1i[3]] = packh2(pa0.w, pa1.w);
        }
        #pragma unroll
        for (int i = 0; i < 3; ++i) {
            if (xval[i]) {
                s2[s2i[i][0]] = packh2(pb0[i].x, pb1[i].x);
                s2[s2i[i][1]] = packh2(pb0[i].y, pb1[i].y);
                s2[s2i[i][2]] = packh2(pb0[i].z, pb1[i].z);
                s2[s2i[i][3]] = packh2(pb0[i].w, pb1[i].w);
            }
        }
    };

    float acc[8][9];
    #pragma unroll
    for (int p = 0; p < 8; ++p)
        #pragma unroll
        for (int d = 0; d < 9; ++d) acc[p][d] = 0.f;

    const int base1 = hr * 512 + wq * 32;
    const int row   = hr + dy;            // 0..11
    const int row7  = row & 7;
    const int base2 = row * 544;

    auto COMPUTE = [&]() {
        uint4 x1v[8];
        #pragma unroll
        for (int p = 0; p < 8; ++p)
            x1v[p] = *reinterpret_cast<const uint4*>(&s1[base1 + ((p ^ (wq & 7)) << 2)]);
        #pragma unroll
        for (int t = 0; t < 16; ++t) {
            const int grp = wq + (t >> 3);
            const int swz = (t & 7) ^ (grp & 7) ^ row7;
            const uint4 x2v =
                *reinterpret_cast<const uint4*>(&s2[base2 + grp * 32 + (swz << 2)]);
            #pragma unroll
            for (int p = 0; p < 8; ++p) {
                const int dxx = t - p;          // compile-time after unroll
                if (dxx >= 0 && dxx <= 8) {
                    float a = acc[p][dxx];
                    a = dot2(x1v[p].x, x2v.x, a);
                    a = dot2(x1v[p].y, x2v.y, a);
                    a = dot2(x1v[p].z, x2v.z, a);
                    a = dot2(x1v[p].w, x2v.w, a);
                    acc[p][dxx] = a;
                }
            }
        }
    };

    // ---------------- pipelined chunk loop ----------------
    LOAD(0);
    WRITE();
    __syncthreads();

    #pragma unroll 1
    for (int cc = 0; cc < NCH; ++cc) {
        if (cc + 1 < NCH) LOAD((size_t)(cc + 1) * CHSTRIDE);
        COMPUTE();
        __syncthreads();
        if (cc + 1 < NCH) WRITE();
        __syncthreads();
    }

    // ---------------- epilogue: mean + leaky_relu + coalesced f32x4 writes ----
    const float inv = 1.0f / 256.0f;
    float* ob = out + ((size_t)(b * 81 + dy * 9) * H_ + (h0 + hr)) * W_ + wq * 8;
    #pragma unroll
    for (int dxx = 0; dxx < 9; ++dxx) {
        float4 o0, o1;
        float v;
        v = acc[0][dxx] * inv; o0.x = v >= 0.f ? v : 0.1f * v;
        v = acc[1][dxx] * inv; o0.y = v >= 0.f ? v : 0.1f * v;
        v = acc[2][dxx] * inv; o0.z = v >= 0.f ? v : 0.1f * v;
        v = acc[3][dxx] * inv; o0.w = v >= 0.f ? v : 0.1f * v;
        v = acc[4][dxx] * inv; o1.x = v >= 0.f ? v : 0.1f * v;
        v = acc[5][dxx] * inv; o1.y = v >= 0.f ? v : 0.1f * v;
        v = acc[6][dxx] * inv; o1.z = v >= 0.f ? v : 0.1f * v;
        v = acc[7][dxx] * inv; o1.w = v >= 0.f ? v : 0.1f * v;
        float* dst = ob + (size_t)dxx * HW;
        *reinterpret_cast<float4*>(dst)     = o0;
        *reinterpret_cast<float4*>(dst + 4) = o1;
    }
}

extern "C" void kernel_launch(void* const* d_in, const int* in_sizes, int n_in,
                              void* d_out, int out_size, void* d_ws, size_t ws_size,
                              hipStream_t stream) {
    const float* x1 = (const float*)d_in[0];
    const float* x2 = (const float*)d_in[1];
    float* out = (float*)d_out;
    corr_kernel<<<dim3(B_ * (H_ / TH)), dim3(576), 0, stream>>>(x1, x2, out);
}

// Round 3
// 144.437 us; speedup vs baseline: 3.8891x; 3.8891x over previous
//
#include <hip/hip_runtime.h>

// PWC-Net correlation (md=4, 81 disps) + leaky_relu(0.1), mean over C=256.
// B=8 C=256 H=96 W=128, f32 in/out.
//
// Block = 9 waves (576 thr), one wave per dy. Tile = 4 rows x 128 w.
// Lane owns 8 consecutive w pixels x 9 dx = 72 f32 accumulators.
// Channels processed in chunks of 8, packed as f16 pairs in LDS,
// consumed via v_dot2_f32_f16 (2 MACs/instr, f32 accumulate).
// COMPUTE split into 2 channel-pair halves (uint2 fragments) to keep
// peak VGPR < 168 (block of 9 waves => 3 waves/SIMD => cap ~168).
// R2 lesson: __launch_bounds__(576,3) capped VGPR at 84 -> acc spilled
// -> 642MB scratch writes. Now: plain __launch_bounds__(576).

#define B_ 8
#define C_ 256
#define H_ 96
#define W_ 128
#define TH 4
#define CC 8
#define NCH (C_ / CC)          // 32 chunks
#define HW (H_ * W_)
#define CHSTRIDE ((size_t)CC * HW)

typedef __fp16 h2_t __attribute__((ext_vector_type(2)));

union H2U { unsigned int u; h2_t h; };

__device__ __forceinline__ h2_t u_as_h2(unsigned int u) { H2U x; x.u = u; return x.h; }

__device__ __forceinline__ unsigned int packh2(float a, float b) {
    H2U x; x.h = __builtin_amdgcn_cvt_pkrtz(a, b); return x.u;
}

#if __has_builtin(__builtin_amdgcn_fdot2)
__device__ __forceinline__ float dot2(unsigned int a, unsigned int b, float c) {
    return __builtin_amdgcn_fdot2(u_as_h2(a), u_as_h2(b), c, false);
}
#else
__device__ __forceinline__ float dot2(unsigned int a, unsigned int b, float c) {
    h2_t ha = u_as_h2(a), hb = u_as_h2(b);
    return c + (float)ha[0] * (float)hb[0] + (float)ha[1] * (float)hb[1];
}
#endif

__global__ __launch_bounds__(576)
void corr_kernel(const float* __restrict__ x1, const float* __restrict__ x2,
                 float* __restrict__ out)
{
    __shared__ __align__(16) unsigned int s1[TH * 128 * 4];   // 2048 u32 = 8 KB
    __shared__ __align__(16) unsigned int s2[12 * 544];       // 6528 u32 = 25.5 KB

    const int bid = blockIdx.x;
    const int b   = bid & 7;          // XCD == batch (round-robin dispatch)
    const int h0  = (bid >> 3) * TH;
    const int tid = threadIdx.x;
    const int dy  = tid >> 6;         // wave id = dy (0..8)
    const int lane = tid & 63;
    const int hr  = lane >> 4;        // 0..3  (h row within tile)
    const int wq  = lane & 15;        // 16 groups of 8 w pixels

    // zero x2 LDS once; invalid (padding) slots are never written again
    for (int i = tid; i < 12 * 544; i += 576) s2[i] = 0u;

    // ---------------- staging task setup (fixed per thread) ----------------
    // x1: tid<512 -> (cpx fastest, then w4, then row). Compressed write
    // indices: idx_k = c1 + ((k ^ l1) << 2)
    const int cpx = tid & 3;
    const int w4  = (tid >> 2) & 31;
    const int rx  = (tid >> 7) & 3;
    const bool x1act = (tid < 512);
    const float* a0p = x1 + (((size_t)(b * C_ + 2 * cpx)) * H_ + (h0 + rx)) * W_ + w4 * 4;
    const int y1 = (w4 >> 1) & 7;
    const int c1 = rx * 512 + (w4 >> 1) * 32
                 + (((((w4 & 1) << 2)) ^ (y1 & 4)) << 2) + cpx;
    const int l1 = y1 & 3;

    // x2: 1632 float4-pair tasks = 4cp x 34groups x 12rows, 3 rounds of 576
    // idx_k = c2[i] + ((k ^ l2[i]) << 2)
    const float* b0p[3];
    int  c2[3], l2[3];
    bool xval[3];
    #pragma unroll
    for (int i = 0; i < 3; ++i) {
        int u = tid + i * 576;
        bool act = (u < 1632);
        int cp2  = u & 3;
        int rest = u >> 2;            // 0..407 when active
        int g = rest % 34;
        int r = rest / 34;
        if (!act) { cp2 = 0; g = 1; r = 0; }
        int hh = h0 + r - 4;
        bool v = act && (hh >= 0) && (hh < H_) && (g >= 1) && (g <= 32);
        xval[i] = v;
        int hhc = v ? hh : 0;
        b0p[i] = x2 + (((size_t)(b * C_ + 2 * cp2)) * H_ + hhc) * W_ + (g * 4 - 4);
        int xx = ((g >> 1) & 7) ^ (r & 7);
        c2[i] = r * 544 + (g >> 1) * 32
              + ((((g & 1) << 2) ^ (xx & 4)) << 2) + cp2;
        l2[i] = xx & 3;
    }

    // prefetch registers
    float4 pa0, pa1, pb0[3], pb1[3];

    auto LOAD = [&](size_t off) {
        if (x1act) {
            pa0 = *reinterpret_cast<const float4*>(a0p + off);
            pa1 = *reinterpret_cast<const float4*>(a0p + off + HW);
        }
        #pragma unroll
        for (int i = 0; i < 3; ++i) {
            if (xval[i]) {
                pb0[i] = *reinterpret_cast<const float4*>(b0p[i] + off);
                pb1[i] = *reinterpret_cast<const float4*>(b0p[i] + off + HW);
            }
        }
    };
    auto WRITE = [&]() {
        if (x1act) {
            s1[c1 + ((0 ^ l1) << 2)] = packh2(pa0.x, pa1.x);
            s1[c1 + ((1 ^ l1) << 2)] = packh2(pa0.y, pa1.y);
            s1[c1 + ((2 ^ l1) << 2)] = packh2(pa0.z, pa1.z);
            s1[c1 + ((3 ^ l1) << 2)] = packh2(pa0.w, pa1.w);
        }
        #pragma unroll
        for (int i = 0; i < 3; ++i) {
            if (xval[i]) {
                s2[c2[i] + ((0 ^ l2[i]) << 2)] = packh2(pb0[i].x, pb1[i].x);
                s2[c2[i] + ((1 ^ l2[i]) << 2)] = packh2(pb0[i].y, pb1[i].y);
                s2[c2[i] + ((2 ^ l2[i]) << 2)] = packh2(pb0[i].z, pb1[i].z);
                s2[c2[i] + ((3 ^ l2[i]) << 2)] = packh2(pb0[i].w, pb1[i].w);
            }
        }
    };

    float acc[8][9];
    #pragma unroll
    for (int p = 0; p < 8; ++p)
        #pragma unroll
        for (int d = 0; d < 9; ++d) acc[p][d] = 0.f;

    const int base1 = hr * 512 + wq * 32;
    const int row   = hr + dy;            // 0..11
    const int row7  = row & 7;
    const int base2 = row * 544;

    auto COMPUTE = [&]() {
        #pragma unroll 1
        for (int half = 0; half < 2; ++half) {
            uint2 x1v[8];
            #pragma unroll
            for (int p = 0; p < 8; ++p)
                x1v[p] = *reinterpret_cast<const uint2*>(
                    &s1[base1 + ((p ^ (wq & 7)) << 2) + half * 2]);
            #pragma unroll
            for (int t = 0; t < 16; ++t) {
                const int grp = wq + (t >> 3);
                const int swz = (t & 7) ^ (grp & 7) ^ row7;
                const uint2 x2v = *reinterpret_cast<const uint2*>(
                    &s2[base2 + grp * 32 + (swz << 2) + half * 2]);
                #pragma unroll
                for (int p = 0; p < 8; ++p) {
                    const int dxx = t - p;          // compile-time after unroll
                    if (dxx >= 0 && dxx <= 8) {
                        float a = acc[p][dxx];
                        a = dot2(x1v[p].x, x2v.x, a);
                        a = dot2(x1v[p].y, x2v.y, a);
                        acc[p][dxx] = a;
                    }
                }
            }
        }
    };

    // ---------------- pipelined chunk loop ----------------
    LOAD(0);
    WRITE();
    __syncthreads();

    #pragma unroll 1
    for (int cc = 0; cc < NCH; ++cc) {
        if (cc + 1 < NCH) LOAD((size_t)(cc + 1) * CHSTRIDE);
        COMPUTE();
        __syncthreads();
        if (cc + 1 < NCH) WRITE();
        __syncthreads();
    }

    // ---------------- epilogue: mean + leaky_relu + coalesced f32x4 writes ----
    const float inv = 1.0f / 256.0f;
    float* ob = out + ((size_t)(b * 81 + dy * 9) * H_ + (h0 + hr)) * W_ + wq * 8;
    #pragma unroll
    for (int dxx = 0; dxx < 9; ++dxx) {
        float4 o0, o1;
        float v;
        v = acc[0][dxx] * inv; o0.x = v >= 0.f ? v : 0.1f * v;
        v = acc[1][dxx] * inv; o0.y = v >= 0.f ? v : 0.1f * v;
        v = acc[2][dxx] * inv; o0.z = v >= 0.f ? v : 0.1f * v;
        v = acc[3][dxx] * inv; o0.w = v >= 0.f ? v : 0.1f * v;
        v = acc[4][dxx] * inv; o1.x = v >= 0.f ? v : 0.1f * v;
        v = acc[5][dxx] * inv; o1.y = v >= 0.f ? v : 0.1f * v;
        v = acc[6][dxx] * inv; o1.z = v >= 0.f ? v : 0.1f * v;
        v = acc[7][dxx] * inv; o1.w = v >= 0.f ? v : 0.1f * v;
        float* dst = ob + (size_t)dxx * HW;
        *reinterpret_cast<float4*>(dst)     = o0;
        *reinterpret_cast<float4*>(dst + 4) = o1;
    }
}

extern "C" void kernel_launch(void* const* d_in, const int* in_sizes, int n_in,
                              void* d_out, int out_size, void* d_ws, size_t ws_size,
                              hipStream_t stream) {
    const float* x1 = (const float*)d_in[0];
    const float* x2 = (const float*)d_in[1];
    float* out = (float*)d_out;
    corr_kernel<<<dim3(B_ * (H_ / TH)), dim3(576), 0, stream>>>(x1, x2, out);
}